// Round 5
// baseline (464.412 us; speedup 1.0000x reference)
//
#include <hip/hip_runtime.h>
#include <math.h>

typedef __attribute__((ext_vector_type(8))) short bf16x8;
typedef __attribute__((ext_vector_type(4))) short bf16x4;
typedef __attribute__((ext_vector_type(2))) short bf16x2;
typedef __attribute__((ext_vector_type(4))) float f32x4;

#define NH 12
#define HD 64
#define C0 768
#define C3 2304
#define LS 256

static __device__ __forceinline__ float bf2f(short u) {
  union { unsigned int i; float f; } c;
  c.i = ((unsigned int)(unsigned short)u) << 16;
  return c.f;
}
static __device__ __forceinline__ short f2bf(float f) {
  union { float f; unsigned int i; } c; c.f = f;
  unsigned int x = c.i;
  x += 0x7fffu + ((x >> 16) & 1u);
  return (short)(x >> 16);
}
static __device__ __forceinline__ unsigned pk2(float a, float b) {
  return (unsigned)(unsigned short)f2bf(a) | ((unsigned)(unsigned short)f2bf(b) << 16);
}

// async global->LDS, 16B per lane; LDS dest is wave-uniform base + lane*16
static __device__ __forceinline__ void gload_lds16(const short* g, const short* l) {
  unsigned long long ga = (unsigned long long)g;
  unsigned int la = (unsigned int)(unsigned long long)l;
  __builtin_amdgcn_global_load_lds(
      (const __attribute__((address_space(1))) void*)ga,
      (__attribute__((address_space(3))) void*)la, 16, 0, 0);
}

// ---------------- cast fp32 -> bf16 (vectorized) ----------------
__global__ __launch_bounds__(256) void cast_kernel(const float* __restrict__ in,
                                                   short* __restrict__ out, int nquads) {
  int i = blockIdx.x * blockDim.x + threadIdx.x;
  int stride = gridDim.x * blockDim.x;
  for (; i < nquads; i += stride) {
    float4 v = ((const float4*)in)[i];
    bf16x4 o = { f2bf(v.x), f2bf(v.y), f2bf(v.z), f2bf(v.w) };
    ((bf16x4*)out)[i] = o;
  }
}

// ---------------- cast + transpose: in[K][N] fp32 -> out[N][K] bf16 ----------------
__global__ __launch_bounds__(256) void cast_transpose_kernel(const float* __restrict__ in,
                                                             short* __restrict__ out,
                                                             int K, int N) {
  __shared__ float tile[32][33];
  int n0 = blockIdx.x * 32, k0 = blockIdx.y * 32;
  int tx = threadIdx.x & 31, ty = threadIdx.x >> 5;
#pragma unroll
  for (int i = 0; i < 32; i += 8)
    tile[ty + i][tx] = in[(long)(k0 + ty + i) * N + n0 + tx];
  __syncthreads();
#pragma unroll
  for (int i = 0; i < 32; i += 8)
    out[(long)(n0 + ty + i) * K + k0 + tx] = f2bf(tile[tx][ty + i]);
}

// ---------------- RoPE table ----------------
__global__ void rope_tab_kernel(float* __restrict__ cost, float* __restrict__ sint) {
  int t = blockIdx.x, d = threadIdx.x;
  int i = d & 31;
  float freq = powf(10000.0f, -(float)(4 * i + 1) / 64.0f);
  float th = (float)t * freq;
  cost[t * 64 + d] = cosf(th);
  sint[t * 64 + d] = sinf(th);
}

// ---------------- 256x256 8-phase bf16 GEMM: A[M][K], Bt[N][K] row-major ----------------
// 8 waves (2M x 4N), per-wave 128x64 out, BK=64, 2 K-tiles/iter, 8 phases/iter.
// LDS 128 KiB = 2 buffers x (A 256x64 + B 256x64). global_load_lds w16, source
// pre-swizzled chunk c^=(row&7); ds_read applies same XOR (both-sides, conflict-free).
// Race-free by construction: all ds_reads of a tile complete at phase-start
// lgkmcnt(0) before that phase's closing barrier; same-buffer staging starts the
// following phase. vmcnt(4) only at phases 4/8 (counted, never 0 in-loop).
#define PH_PRE                                         \
  __builtin_amdgcn_s_barrier();                        \
  asm volatile("s_waitcnt lgkmcnt(0)" ::: "memory");   \
  __builtin_amdgcn_sched_barrier(0);                   \
  __builtin_amdgcn_s_setprio(1);
#define PH_POST                                        \
  __builtin_amdgcn_s_setprio(0);                       \
  __builtin_amdgcn_s_barrier();
#define PH_POSTV                                       \
  __builtin_amdgcn_s_setprio(0);                       \
  asm volatile("s_waitcnt vmcnt(4)" ::: "memory");     \
  __builtin_amdgcn_s_barrier();
#define MMQ(MH, NP, AF)                                                            \
  { _Pragma("unroll") for (int f_ = 0; f_ < 4; ++f_)                               \
      _Pragma("unroll") for (int n_ = 0; n_ < 2; ++n_)                             \
        _Pragma("unroll") for (int k_ = 0; k_ < 2; ++k_)                           \
          acc[(MH)*4 + f_][(NP)*2 + n_] = __builtin_amdgcn_mfma_f32_16x16x32_bf16( \
              AF[f_*2 + k_], bfv[((NP)*2 + n_)*2 + k_],                            \
              acc[(MH)*4 + f_][(NP)*2 + n_], 0, 0, 0); }

template <int OUT_F32>
__global__ __launch_bounds__(512, 2) void gemm8p_kernel(const short* __restrict__ A,
                                                        const short* __restrict__ Bt,
                                                        void* __restrict__ Cout,
                                                        int N, int K, int nbn) {
  __shared__ short lds[65536];  // 128 KiB
  int t = threadIdx.x, lane = t & 63, wave = t >> 6;
  int lr = lane & 15, lg = lane >> 4;
  int wm = (wave >> 2) * 128, wn = (wave & 3) * 64;
  int id = blockIdx.x;
  int cpx = gridDim.x >> 3;                 // grid % 8 == 0
  int sw = (id & 7) * cpx + (id >> 3);      // bijective XCD swizzle
  int bm = sw / nbn, bn = sw % nbn;
  const short* Abase = A + (long)bm * 256 * K;
  const short* Bbase = Bt + (long)bn * 256 * K;
  int srow = t >> 3;
  int scol = ((t & 7) ^ (srow & 7)) * 8;
  int smax = K >> 4;                        // 4 * (K/64) half-tiles total

  f32x4 acc[8][4];
#pragma unroll
  for (int m = 0; m < 8; ++m)
#pragma unroll
    for (int n = 0; n < 4; ++n) acc[m][n] = (f32x4){0.f, 0.f, 0.f, 0.f};

  auto STAGE = [&](int s) {
    if (s < smax) {
      int T = s >> 2, q = s & 3;
      const short* base = (q < 2) ? Abase : Bbase;
      const short* g = base + (long)((q & 1) * 128 + srow) * K + T * 64 + scol;
      int lb = (T & 1) * 32768 + (q >> 1) * 16384 + (q & 1) * 8192 + t * 8;
      gload_lds16(g, &lds[lb]);
      gload_lds16(g + (long)64 * K, &lds[lb + 4096]);
    }
  };
  auto LDA = [&](bf16x8* d, int b, int mh) {
#pragma unroll
    for (int f = 0; f < 4; ++f) {
      int R = wm + mh * 64 + f * 16 + lr;
      int rb = b * 32768 + R * 64;
      int s8 = R & 7;
      d[f * 2 + 0] = *(bf16x8*)&lds[rb + ((lg ^ s8) << 3)];
      d[f * 2 + 1] = *(bf16x8*)&lds[rb + (((4 + lg) ^ s8) << 3)];
    }
  };
  auto LDBH = [&](bf16x8* d, int b, int nh) {
#pragma unroll
    for (int j = 0; j < 2; ++j) {
      int R = wn + (nh * 2 + j) * 16 + lr;
      int rb = b * 32768 + 16384 + R * 64;
      int s8 = R & 7;
      d[(nh * 2 + j) * 2 + 0] = *(bf16x8*)&lds[rb + ((lg ^ s8) << 3)];
      d[(nh * 2 + j) * 2 + 1] = *(bf16x8*)&lds[rb + (((4 + lg) ^ s8) << 3)];
    }
  };

  // prologue: tile0 q0-3, tile1 q0,q1 ; wait tile0 resident (4 gloads in flight)
  STAGE(0); STAGE(1); STAGE(2); STAGE(3); STAGE(4); STAGE(5);
  asm volatile("s_waitcnt vmcnt(4)" ::: "memory");
  __builtin_amdgcn_s_barrier();

  int iters = K >> 7;  // 2 K-tiles per iter
  for (int i = 0; i < iters; ++i) {
    int si = 8 * i + 6;
    bf16x8 af0[8], af1[8], bfv[8];
    // p1: tile 2i (buf0)
    LDA(af0, 0, 0); LDBH(bfv, 0, 0);
    STAGE(si + 0);
    PH_PRE; MMQ(0, 0, af0); PH_POST;
    // p2
    LDA(af1, 0, 1); LDBH(bfv, 0, 1);
    STAGE(si + 1);
    PH_PRE; MMQ(0, 1, af0); PH_POST;
    // p3
    STAGE(si + 2);
    PH_PRE; MMQ(1, 0, af1); PH_POST;
    // p4
    STAGE(si + 3);
    PH_PRE; MMQ(1, 1, af1); PH_POSTV;
    // p5: tile 2i+1 (buf1)
    LDA(af0, 1, 0); LDBH(bfv, 1, 0);
    STAGE(si + 4);
    PH_PRE; MMQ(0, 0, af0); PH_POST;
    // p6
    LDA(af1, 1, 1); LDBH(bfv, 1, 1);
    STAGE(si + 5);
    PH_PRE; MMQ(0, 1, af0); PH_POST;
    // p7
    STAGE(si + 6);
    PH_PRE; MMQ(1, 0, af1); PH_POST;
    // p8
    STAGE(si + 7);
    PH_PRE; MMQ(1, 1, af1); PH_POSTV;
  }

  // epilogue: D layout col=lane&15, row=(lane>>4)*4+r
  long crow0 = (long)bm * 256 + wm;
  long ccol0 = (long)bn * 256 + wn;
#pragma unroll
  for (int f = 0; f < 8; ++f)
#pragma unroll
    for (int n = 0; n < 4; ++n)
#pragma unroll
      for (int r = 0; r < 4; ++r) {
        long row = crow0 + (f >> 2) * 64 + (f & 3) * 16 + lg * 4 + r;
        long col = ccol0 + n * 16 + lr;
        float v = acc[f][n][r];
        if (OUT_F32) ((float*)Cout)[row * N + col] = v;
        else ((short*)Cout)[row * N + col] = f2bf(v);
      }
}

// ---------------- fused RMSNorm(q,k) + RoPE, in place (unchanged) ----------------
__global__ __launch_bounds__(384) void norm_rope_kernel(short* __restrict__ QKV,
    const float* __restrict__ w_ln, const float* __restrict__ cost,
    const float* __restrict__ sint) {
  int row = blockIdx.x;
  int t = row & 255;
  int i = threadIdx.x;
  long base = (long)row * C3;
  bf16x2 q2 = *(bf16x2*)&QKV[base + 2 * i];
  bf16x2 k2 = *(bf16x2*)&QKV[base + C0 + 2 * i];
  float qa = bf2f(q2.x), qb = bf2f(q2.y);
  float ka = bf2f(k2.x), kb = bf2f(k2.y);
  float sq = qa * qa + qb * qb;
  float sk = ka * ka + kb * kb;
#pragma unroll
  for (int o = 32; o > 0; o >>= 1) {
    sq += __shfl_down(sq, o);
    sk += __shfl_down(sk, o);
  }
  __shared__ float red[2][6];
  int wv = i >> 6;
  if ((i & 63) == 0) { red[0][wv] = sq; red[1][wv] = sk; }
  __syncthreads();
  float s0 = 0.f, s1 = 0.f;
#pragma unroll
  for (int w = 0; w < 6; ++w) { s0 += red[0][w]; s1 += red[1][w]; }
  float rq = rsqrtf(s0 * (1.0f / 768.0f) + 1e-6f);
  float rk = rsqrtf(s1 * (1.0f / 768.0f) + 1e-6f);
  float wl0 = w_ln[2 * i], wl1 = w_ln[2 * i + 1];
  float qn0 = qa * rq * wl0, qn1 = qb * rq * wl1;
  float kn0 = ka * rk * wl0, kn1 = kb * rk * wl1;
  int d0 = (2 * i) & 63;
  float c0 = cost[t * 64 + d0], c1 = cost[t * 64 + d0 + 1];
  float s0r = sint[t * 64 + d0], s1r = sint[t * 64 + d0 + 1];
  bf16x2 qo, ko;
  qo.x = f2bf(qn0 * c0 - qn1 * s0r);
  qo.y = f2bf(qn1 * c1 + qn0 * s1r);
  ko.x = f2bf(kn0 * c0 - kn1 * s0r);
  ko.y = f2bf(kn1 * c1 + kn0 * s1r);
  *(bf16x2*)&QKV[base + 2 * i] = qo;
  *(bf16x2*)&QKV[base + C0 + 2 * i] = ko;
}

// ---------------- block-causal attention (unchanged from round 4) ----------------
__global__ __launch_bounds__(512, 3) void attn_kernel(const short* __restrict__ QKV,
                                                      short* __restrict__ Y) {
  __shared__ short Ks[256 * 64];
  __shared__ short Vt[64 * 256];
  int blk = blockIdx.x;
  int bg = blk / NH, h = blk % NH;
  const long base = (long)bg * LS * C3 + h * HD;
  int tid = threadIdx.x, lane = tid & 63, wave = tid >> 6;
  int lr = lane & 15, lg = lane >> 4;

#pragma unroll
  for (int it = 0; it < 4; ++it) {
    int q = it * 512 + tid;
    int row = q >> 3, cp = q & 7;
    int gcp = cp ^ (row & 7);
    gload_lds16(QKV + base + (long)row * C3 + C0 + gcp * 8, &Ks[q * 8]);
  }
#pragma unroll
  for (int it = 0; it < 8; ++it) {
    int e = tid * 4 + it * 2048;
    int k = e >> 6, n = e & 63;
    bf16x4 v = *(const bf16x4*)&QKV[base + (long)k * C3 + 2 * C0 + n];
#pragma unroll
    for (int j = 0; j < 4; ++j) {
      int nn = n + j;
      Vt[nn * 256 + (((k >> 3) ^ (nn & 7)) << 3) + (k & 7)] = v[j];
    }
  }
  asm volatile("s_waitcnt vmcnt(0)" ::: "memory");
  __syncthreads();

  int addrA = (((lane >> 4) & 1) * 32 + lr) * 4;
  int addrB = addrA + 64;
  bool selhi = (lane & 32) != 0;

  for (int tt = 0; tt < 2; ++tt) {
    int tile = (tt == 0) ? wave : (15 - wave);
    int m0 = tile * 16;
    bf16x8 qf[2];
#pragma unroll
    for (int ks = 0; ks < 2; ++ks)
      qf[ks] = *(const bf16x8*)&QKV[base + (long)(m0 + lr) * C3 + ks * 32 + lg * 8];

    f32x4 zero4 = {0.f, 0.f, 0.f, 0.f};
    f32x4 accs[16];
#pragma unroll
    for (int n = 0; n < 16; ++n) accs[n] = zero4;

    __builtin_amdgcn_s_setprio(1);
#pragma unroll
    for (int n = 0; n < 16; ++n) {
      if (n <= tile) {
        int row = n * 16 + lr, sw = row & 7;
        bf16x8 k0 = *(bf16x8*)&Ks[row * 64 + ((lg ^ sw) << 3)];
        bf16x8 k1 = *(bf16x8*)&Ks[row * 64 + (((4 + lg) ^ sw) << 3)];
        accs[n] = __builtin_amdgcn_mfma_f32_16x16x32_bf16(k0, qf[0], accs[n], 0, 0, 0);
        accs[n] = __builtin_amdgcn_mfma_f32_16x16x32_bf16(k1, qf[1], accs[n], 0, 0, 0);
      }
    }
    __builtin_amdgcn_s_setprio(0);

    float mloc = -1e30f;
#pragma unroll
    for (int n = 0; n < 16; ++n) {
      if (n <= tile) {
#pragma unroll
        for (int r = 0; r < 4; ++r) {
          float v = accs[n][r];
          if (n == tile) v = (lg * 4 + r <= lr) ? v : -1e30f;
          accs[n][r] = v;
          mloc = fmaxf(mloc, v);
        }
      }
    }
    mloc = fmaxf(mloc, __shfl_xor(mloc, 16));
    mloc = fmaxf(mloc, __shfl_xor(mloc, 32));
    float s = 0.f;
#pragma unroll
    for (int n = 0; n < 16; ++n) {
      if (n <= tile) {
#pragma unroll
        for (int r = 0; r < 4; ++r) {
          float p = __expf((accs[n][r] - mloc) * 0.125f);
          accs[n][r] = p;
          s += p;
        }
      }
    }
    s += __shfl_xor(s, 16);
    s += __shfl_xor(s, 32);
    float rs = 1.0f / s;
    float rv[4];
#pragma unroll
    for (int r = 0; r < 4; ++r) {
      union { float f; int i; } c; c.f = rs;
      union { int i; float f; } o;
      o.i = __builtin_amdgcn_ds_bpermute((lg * 4 + r) * 4, c.i);
      rv[r] = o.f;
    }

    int ktmax = (m0 + 15) >> 5;
    f32x4 yacc[4];
#pragma unroll
    for (int n2 = 0; n2 < 4; ++n2) yacc[n2] = zero4;
#pragma unroll
    for (int kt = 0; kt < 8; ++kt) {
      if (kt <= ktmax) {
        int n0 = 2 * kt, n1 = 2 * kt + 1;
        unsigned a01_0 = pk2(accs[n0][0], accs[n0][1]);
        unsigned a23_0 = pk2(accs[n0][2], accs[n0][3]);
        unsigned a01_1 = (n1 <= tile) ? pk2(accs[n1][0], accs[n1][1]) : 0u;
        unsigned a23_1 = (n1 <= tile) ? pk2(accs[n1][2], accs[n1][3]) : 0u;
        union { unsigned u[4]; bf16x8 v; } af;
        unsigned g0a = (unsigned)__builtin_amdgcn_ds_bpermute(addrA, (int)a01_0);
        unsigned g0b = (unsigned)__builtin_amdgcn_ds_bpermute(addrA, (int)a01_1);
        unsigned g1a = (unsigned)__builtin_amdgcn_ds_bpermute(addrA, (int)a23_0);
        unsigned g1b = (unsigned)__builtin_amdgcn_ds_bpermute(addrA, (int)a23_1);
        unsigned g2a = (unsigned)__builtin_amdgcn_ds_bpermute(addrB, (int)a01_0);
        unsigned g2b = (unsigned)__builtin_amdgcn_ds_bpermute(addrB, (int)a01_1);
        unsigned g3a = (unsigned)__builtin_amdgcn_ds_bpermute(addrB, (int)a23_0);
        unsigned g3b = (unsigned)__builtin_amdgcn_ds_bpermute(addrB, (int)a23_1);
        af.u[0] = selhi ? g0b : g0a;
        af.u[1] = selhi ? g1b : g1a;
        af.u[2] = selhi ? g2b : g2a;
        af.u[3] = selhi ? g3b : g3a;
        int ac = kt * 32 + lg * 8;
        __builtin_amdgcn_s_setprio(1);
#pragma unroll
        for (int n2 = 0; n2 < 4; ++n2) {
          int vn = n2 * 16 + lr;
          bf16x8 vb = *(bf16x8*)&Vt[vn * 256 + (((ac >> 3) ^ (vn & 7)) << 3)];
          yacc[n2] = __builtin_amdgcn_mfma_f32_16x16x32_bf16(af.v, vb, yacc[n2], 0, 0, 0);
        }
        __builtin_amdgcn_s_setprio(0);
      }
    }

#pragma unroll
    for (int n2 = 0; n2 < 4; ++n2) {
#pragma unroll
      for (int r = 0; r < 4; ++r) {
        int row = m0 + lg * 4 + r, d = n2 * 16 + lr;
        Y[((long)(bg * LS + row)) * C0 + h * HD + d] = f2bf(yacc[n2][r] * rv[r]);
      }
    }
  }
}

extern "C" void kernel_launch(void* const* d_in, const int* in_sizes, int n_in,
                              void* d_out, int out_size, void* d_ws, size_t ws_size,
                              hipStream_t stream) {
  (void)in_sizes; (void)n_in; (void)out_size; (void)ws_size;
  const float* x = (const float*)d_in[0];
  const float* w_qkv = (const float*)d_in[1];
  const float* w_ln = (const float*)d_in[2];
  const float* w_proj = (const float*)d_in[3];
  float* out = (float*)d_out;

  char* ws = (char*)d_ws;
  short* Xb      = (short*)(ws + 0);
  short* QKV     = (short*)(ws + 50331648);
  short* Yb      = (short*)(ws + 201326592);
  short* WqkvT   = (short*)(ws + 251658240);
  short* WprojT  = (short*)(ws + 255197184);
  float* cost    = (float*)(ws + 256376832);
  float* sint    = (float*)(ws + 256442368);

  cast_kernel<<<2048, 256, 0, stream>>>(x, Xb, (4 * 8192 * C0) / 4);
  cast_transpose_kernel<<<dim3(C3 / 32, C0 / 32), 256, 0, stream>>>(w_qkv, WqkvT, C0, C3);
  cast_transpose_kernel<<<dim3(C0 / 32, C0 / 32), 256, 0, stream>>>(w_proj, WprojT, C0, C0);
  rope_tab_kernel<<<256, 64, 0, stream>>>(cost, sint);

  // QKV = X @ Wqkv : M=32768, N=2304, K=768 ; grid 9*128=1152 (%8==0)
  gemm8p_kernel<0><<<(C3 / 256) * (32768 / 256), 512, 0, stream>>>(Xb, WqkvT, QKV,
                                                                   C3, C0, C3 / 256);
  norm_rope_kernel<<<32768, 384, 0, stream>>>(QKV, w_ln, cost, sint);
  attn_kernel<<<128 * NH, 512, 0, stream>>>(QKV, Yb);
  // out = Y @ Wproj : M=32768, N=768, K=768 ; grid 3*128=384 (%8==0)
  gemm8p_kernel<1><<<(C0 / 256) * (32768 / 256), 512, 0, stream>>>(Yb, WprojT, out,
                                                                   C0, C0, C0 / 256);
}

// Round 6
// 324.747 us; speedup vs baseline: 1.4301x; 1.4301x over previous
//
#include <hip/hip_runtime.h>
#include <math.h>

typedef __attribute__((ext_vector_type(8))) short bf16x8;
typedef __attribute__((ext_vector_type(4))) short bf16x4;
typedef __attribute__((ext_vector_type(2))) short bf16x2;
typedef __attribute__((ext_vector_type(4))) float f32x4;

#define NH 12
#define HD 64
#define C0 768
#define C3 2304
#define LS 256

static __device__ __forceinline__ float bf2f(short u) {
  union { unsigned int i; float f; } c;
  c.i = ((unsigned int)(unsigned short)u) << 16;
  return c.f;
}
static __device__ __forceinline__ short f2bf(float f) {
  union { float f; unsigned int i; } c; c.f = f;
  unsigned int x = c.i;
  x += 0x7fffu + ((x >> 16) & 1u);
  return (short)(x >> 16);
}
static __device__ __forceinline__ unsigned pk2(float a, float b) {
  return (unsigned)(unsigned short)f2bf(a) | ((unsigned)(unsigned short)f2bf(b) << 16);
}

// async global->LDS, 16B per lane; LDS dest is wave-uniform base + lane*16
static __device__ __forceinline__ void gload_lds16(const short* g, const short* l) {
  unsigned long long ga = (unsigned long long)g;
  unsigned int la = (unsigned int)(unsigned long long)l;
  __builtin_amdgcn_global_load_lds(
      (const __attribute__((address_space(1))) void*)ga,
      (__attribute__((address_space(3))) void*)la, 16, 0, 0);
}

// ---------------- cast fp32 -> bf16 (vectorized) ----------------
__global__ __launch_bounds__(256) void cast_kernel(const float* __restrict__ in,
                                                   short* __restrict__ out, int nquads) {
  int i = blockIdx.x * blockDim.x + threadIdx.x;
  int stride = gridDim.x * blockDim.x;
  for (; i < nquads; i += stride) {
    float4 v = ((const float4*)in)[i];
    bf16x4 o = { f2bf(v.x), f2bf(v.y), f2bf(v.z), f2bf(v.w) };
    ((bf16x4*)out)[i] = o;
  }
}

// ---------------- cast + transpose: in[K][N] fp32 -> out[N][K] bf16 ----------------
__global__ __launch_bounds__(256) void cast_transpose_kernel(const float* __restrict__ in,
                                                             short* __restrict__ out,
                                                             int K, int N) {
  __shared__ float tile[32][33];
  int n0 = blockIdx.x * 32, k0 = blockIdx.y * 32;
  int tx = threadIdx.x & 31, ty = threadIdx.x >> 5;
#pragma unroll
  for (int i = 0; i < 32; i += 8)
    tile[ty + i][tx] = in[(long)(k0 + ty + i) * N + n0 + tx];
  __syncthreads();
#pragma unroll
  for (int i = 0; i < 32; i += 8)
    out[(long)(n0 + ty + i) * K + k0 + tx] = f2bf(tile[tx][ty + i]);
}

// ---------------- RoPE table ----------------
__global__ void rope_tab_kernel(float* __restrict__ cost, float* __restrict__ sint) {
  int t = blockIdx.x, d = threadIdx.x;
  int i = d & 31;
  float freq = powf(10000.0f, -(float)(4 * i + 1) / 64.0f);
  float th = (float)t * freq;
  cost[t * 64 + d] = cosf(th);
  sint[t * 64 + d] = sinf(th);
}

// ---------------- 256x256 8-phase bf16 GEMM, register-lean port ----------------
// 8 waves (2M x 4N), per-wave 128x64 out, BK=64, 2 K-tiles/iter, 8 phases/iter.
// acc = 128 AGPR -> arch-VGPR hard cap 128 at 2 waves/SIMD. Operands kept to
// af[8]+bfv[8] = 64 VGPR: A-half0 loaded p1, OVERWRITTEN with A-half1 at p3.
// Stage order per tile: B-low,B-high,A-low,A-high (q = slot^2) so p3's A-reads
// are disjoint from the B region staged in p3/p4 (verified phase-by-phase).
// Tail stages past K reload tile 0 into dead regions: uniform vmcnt(4) stays
// correct on the last iteration (round-5 latent race fixed).
#define PH_PRE                                         \
  __builtin_amdgcn_s_barrier();                        \
  asm volatile("s_waitcnt lgkmcnt(0)" ::: "memory");   \
  __builtin_amdgcn_sched_barrier(0);                   \
  __builtin_amdgcn_s_setprio(1);
#define PH_POST                                        \
  __builtin_amdgcn_s_setprio(0);                       \
  __builtin_amdgcn_s_barrier();
#define PH_POSTV                                       \
  __builtin_amdgcn_s_setprio(0);                       \
  asm volatile("s_waitcnt vmcnt(4)" ::: "memory");     \
  __builtin_amdgcn_s_barrier();
#define MMQ(MH, NP)                                                                \
  { _Pragma("unroll") for (int f_ = 0; f_ < 4; ++f_)                               \
      _Pragma("unroll") for (int n_ = 0; n_ < 2; ++n_)                             \
        _Pragma("unroll") for (int k_ = 0; k_ < 2; ++k_)                           \
          acc[(MH)*4 + f_][(NP)*2 + n_] = __builtin_amdgcn_mfma_f32_16x16x32_bf16( \
              af[f_*2 + k_], bfv[((NP)*2 + n_)*2 + k_],                            \
              acc[(MH)*4 + f_][(NP)*2 + n_], 0, 0, 0); }

template <int OUT_F32>
__global__ __launch_bounds__(512, 2) void gemm8p_kernel(const short* __restrict__ A,
                                                        const short* __restrict__ Bt,
                                                        void* __restrict__ Cout,
                                                        int N, int K, int nbn) {
  __shared__ short lds[65536];  // 128 KiB: 2 bufs x (A 256x64 + B 256x64)
  int t = threadIdx.x, lane = t & 63, wave = t >> 6;
  int lr = lane & 15, lg = lane >> 4;
  int wm = (wave >> 2) * 128, wn = (wave & 3) * 64;
  int id = blockIdx.x;
  int cpx = gridDim.x >> 3;                 // grid % 8 == 0
  int sw = (id & 7) * cpx + (id >> 3);      // bijective XCD swizzle
  int bm = sw / nbn, bn = sw % nbn;
  const short* Abase = A + (long)bm * 256 * K;
  const short* Bbase = Bt + (long)bn * 256 * K;
  int srow = t >> 3;
  int scol = ((t & 7) ^ (srow & 7)) * 8;
  int smax = K >> 4;                        // 4 stages per K-tile of 64

  f32x4 acc[8][4];
#pragma unroll
  for (int m = 0; m < 8; ++m)
#pragma unroll
    for (int n = 0; n < 4; ++n) acc[m][n] = (f32x4){0.f, 0.f, 0.f, 0.f};

  bf16x8 af[8], bfv[8];

  auto STAGE = [&](int s) {
    int slot = s & 3;                       // q = slot^2: B,B,A,A order
    int Tg = (s < smax) ? (s >> 2) : 0;     // tail: reload tile0 (dead region)
    const short* base = (slot & 2) ? Abase : Bbase;
    const short* g = base + (long)((slot & 1) * 128 + srow) * K + Tg * 64 + scol;
    int lb = ((s >> 2) & 1) * 32768 + ((slot >> 1) ^ 1) * 16384 + (slot & 1) * 8192 + t * 8;
    gload_lds16(g, &lds[lb]);
    gload_lds16(g + (long)64 * K, &lds[lb + 4096]);
  };
  auto LDA = [&](int b, int mh) {
#pragma unroll
    for (int f = 0; f < 4; ++f) {
      int R = wm + mh * 64 + f * 16 + lr;
      int rb = b * 32768 + R * 64;
      int s8 = R & 7;
      af[f * 2 + 0] = *(bf16x8*)&lds[rb + ((lg ^ s8) << 3)];
      af[f * 2 + 1] = *(bf16x8*)&lds[rb + (((4 + lg) ^ s8) << 3)];
    }
  };
  auto LDB = [&](int b, int nh) {
#pragma unroll
    for (int j = 0; j < 2; ++j) {
      int R = wn + (nh * 2 + j) * 16 + lr;
      int rb = b * 32768 + 16384 + R * 64;
      int s8 = R & 7;
      bfv[(nh * 2 + j) * 2 + 0] = *(bf16x8*)&lds[rb + ((lg ^ s8) << 3)];
      bfv[(nh * 2 + j) * 2 + 1] = *(bf16x8*)&lds[rb + (((4 + lg) ^ s8) << 3)];
    }
  };

  // prologue: tile0 {B,B,A,A} + tile1 {B,B}; vmcnt(4) -> tile0 fully resident
  STAGE(0); STAGE(1); STAGE(2); STAGE(3); STAGE(4); STAGE(5);
  asm volatile("s_waitcnt vmcnt(4)" ::: "memory");
  __builtin_amdgcn_s_barrier();

  int iters = K >> 7;  // 2 K-tiles per iter
  for (int i = 0; i < iters; ++i) {
    int si = 8 * i + 6;
    // p1: tile 2i (buf0), quadrant (m0, n-pair0)
    LDA(0, 0); LDB(0, 0);
    STAGE(si + 0);                       // tile 2i+1: A-low (buf1)
    PH_PRE; MMQ(0, 0); PH_POST;
    // p2: (m0, n-pair1)
    LDB(0, 1);
    STAGE(si + 1);                       // tile 2i+1: A-high (buf1)
    PH_PRE; MMQ(0, 1); PH_POST;
    // p3: (m1, n-pair0) — af overwritten with A-half1
    LDA(0, 1);
    STAGE(si + 2);                       // tile 2i+2: B-low (buf0, reads done p2)
    PH_PRE; MMQ(1, 0); PH_POST;
    // p4: (m1, n-pair1)
    STAGE(si + 3);                       // tile 2i+2: B-high (buf0)
    PH_PRE; MMQ(1, 1); PH_POSTV;         // vmcnt(4): tile 2i+1 fully resident
    // p5: tile 2i+1 (buf1)
    LDA(1, 0); LDB(1, 0);
    STAGE(si + 4);                       // tile 2i+2: A-low (buf0)
    PH_PRE; MMQ(0, 0); PH_POST;
    // p6
    LDB(1, 1);
    STAGE(si + 5);                       // tile 2i+2: A-high (buf0)
    PH_PRE; MMQ(0, 1); PH_POST;
    // p7
    LDA(1, 1);
    STAGE(si + 6);                       // tile 2i+3: B-low (buf1, reads done p6)
    PH_PRE; MMQ(1, 0); PH_POST;
    // p8
    STAGE(si + 7);                       // tile 2i+3: B-high (buf1)
    PH_PRE; MMQ(1, 1); PH_POSTV;         // vmcnt(4): tile 2i+2 fully resident
  }

  // epilogue: D layout col=lane&15, row=(lane>>4)*4+r
  long crow0 = (long)bm * 256 + wm;
  long ccol0 = (long)bn * 256 + wn;
#pragma unroll
  for (int f = 0; f < 8; ++f)
#pragma unroll
    for (int n = 0; n < 4; ++n)
#pragma unroll
      for (int r = 0; r < 4; ++r) {
        long row = crow0 + (f >> 2) * 64 + (f & 3) * 16 + lg * 4 + r;
        long col = ccol0 + n * 16 + lr;
        float v = acc[f][n][r];
        if (OUT_F32) ((float*)Cout)[row * N + col] = v;
        else ((short*)Cout)[row * N + col] = f2bf(v);
      }
}

// ---------------- fused RMSNorm(q,k) + RoPE, in place (unchanged) ----------------
__global__ __launch_bounds__(384) void norm_rope_kernel(short* __restrict__ QKV,
    const float* __restrict__ w_ln, const float* __restrict__ cost,
    const float* __restrict__ sint) {
  int row = blockIdx.x;
  int t = row & 255;
  int i = threadIdx.x;
  long base = (long)row * C3;
  bf16x2 q2 = *(bf16x2*)&QKV[base + 2 * i];
  bf16x2 k2 = *(bf16x2*)&QKV[base + C0 + 2 * i];
  float qa = bf2f(q2.x), qb = bf2f(q2.y);
  float ka = bf2f(k2.x), kb = bf2f(k2.y);
  float sq = qa * qa + qb * qb;
  float sk = ka * ka + kb * kb;
#pragma unroll
  for (int o = 32; o > 0; o >>= 1) {
    sq += __shfl_down(sq, o);
    sk += __shfl_down(sk, o);
  }
  __shared__ float red[2][6];
  int wv = i >> 6;
  if ((i & 63) == 0) { red[0][wv] = sq; red[1][wv] = sk; }
  __syncthreads();
  float s0 = 0.f, s1 = 0.f;
#pragma unroll
  for (int w = 0; w < 6; ++w) { s0 += red[0][w]; s1 += red[1][w]; }
  float rq = rsqrtf(s0 * (1.0f / 768.0f) + 1e-6f);
  float rk = rsqrtf(s1 * (1.0f / 768.0f) + 1e-6f);
  float wl0 = w_ln[2 * i], wl1 = w_ln[2 * i + 1];
  float qn0 = qa * rq * wl0, qn1 = qb * rq * wl1;
  float kn0 = ka * rk * wl0, kn1 = kb * rk * wl1;
  int d0 = (2 * i) & 63;
  float c0 = cost[t * 64 + d0], c1 = cost[t * 64 + d0 + 1];
  float s0r = sint[t * 64 + d0], s1r = sint[t * 64 + d0 + 1];
  bf16x2 qo, ko;
  qo.x = f2bf(qn0 * c0 - qn1 * s0r);
  qo.y = f2bf(qn1 * c1 + qn0 * s1r);
  ko.x = f2bf(kn0 * c0 - kn1 * s0r);
  ko.y = f2bf(kn1 * c1 + kn0 * s1r);
  *(bf16x2*)&QKV[base + 2 * i] = qo;
  *(bf16x2*)&QKV[base + C0 + 2 * i] = ko;
}

// ---------------- block-causal attention (unchanged from round 4) ----------------
__global__ __launch_bounds__(512, 3) void attn_kernel(const short* __restrict__ QKV,
                                                      short* __restrict__ Y) {
  __shared__ short Ks[256 * 64];
  __shared__ short Vt[64 * 256];
  int blk = blockIdx.x;
  int bg = blk / NH, h = blk % NH;
  const long base = (long)bg * LS * C3 + h * HD;
  int tid = threadIdx.x, lane = tid & 63, wave = tid >> 6;
  int lr = lane & 15, lg = lane >> 4;

#pragma unroll
  for (int it = 0; it < 4; ++it) {
    int q = it * 512 + tid;
    int row = q >> 3, cp = q & 7;
    int gcp = cp ^ (row & 7);
    gload_lds16(QKV + base + (long)row * C3 + C0 + gcp * 8, &Ks[q * 8]);
  }
#pragma unroll
  for (int it = 0; it < 8; ++it) {
    int e = tid * 4 + it * 2048;
    int k = e >> 6, n = e & 63;
    bf16x4 v = *(const bf16x4*)&QKV[base + (long)k * C3 + 2 * C0 + n];
#pragma unroll
    for (int j = 0; j < 4; ++j) {
      int nn = n + j;
      Vt[nn * 256 + (((k >> 3) ^ (nn & 7)) << 3) + (k & 7)] = v[j];
    }
  }
  asm volatile("s_waitcnt vmcnt(0)" ::: "memory");
  __syncthreads();

  int addrA = (((lane >> 4) & 1) * 32 + lr) * 4;
  int addrB = addrA + 64;
  bool selhi = (lane & 32) != 0;

  for (int tt = 0; tt < 2; ++tt) {
    int tile = (tt == 0) ? wave : (15 - wave);
    int m0 = tile * 16;
    bf16x8 qf[2];
#pragma unroll
    for (int ks = 0; ks < 2; ++ks)
      qf[ks] = *(const bf16x8*)&QKV[base + (long)(m0 + lr) * C3 + ks * 32 + lg * 8];

    f32x4 zero4 = {0.f, 0.f, 0.f, 0.f};
    f32x4 accs[16];
#pragma unroll
    for (int n = 0; n < 16; ++n) accs[n] = zero4;

    __builtin_amdgcn_s_setprio(1);
#pragma unroll
    for (int n = 0; n < 16; ++n) {
      if (n <= tile) {
        int row = n * 16 + lr, sw = row & 7;
        bf16x8 k0 = *(bf16x8*)&Ks[row * 64 + ((lg ^ sw) << 3)];
        bf16x8 k1 = *(bf16x8*)&Ks[row * 64 + (((4 + lg) ^ sw) << 3)];
        accs[n] = __builtin_amdgcn_mfma_f32_16x16x32_bf16(k0, qf[0], accs[n], 0, 0, 0);
        accs[n] = __builtin_amdgcn_mfma_f32_16x16x32_bf16(k1, qf[1], accs[n], 0, 0, 0);
      }
    }
    __builtin_amdgcn_s_setprio(0);

    float mloc = -1e30f;
#pragma unroll
    for (int n = 0; n < 16; ++n) {
      if (n <= tile) {
#pragma unroll
        for (int r = 0; r < 4; ++r) {
          float v = accs[n][r];
          if (n == tile) v = (lg * 4 + r <= lr) ? v : -1e30f;
          accs[n][r] = v;
          mloc = fmaxf(mloc, v);
        }
      }
    }
    mloc = fmaxf(mloc, __shfl_xor(mloc, 16));
    mloc = fmaxf(mloc, __shfl_xor(mloc, 32));
    float s = 0.f;
#pragma unroll
    for (int n = 0; n < 16; ++n) {
      if (n <= tile) {
#pragma unroll
        for (int r = 0; r < 4; ++r) {
          float p = __expf((accs[n][r] - mloc) * 0.125f);
          accs[n][r] = p;
          s += p;
        }
      }
    }
    s += __shfl_xor(s, 16);
    s += __shfl_xor(s, 32);
    float rs = 1.0f / s;
    float rv[4];
#pragma unroll
    for (int r = 0; r < 4; ++r) {
      union { float f; int i; } c; c.f = rs;
      union { int i; float f; } o;
      o.i = __builtin_amdgcn_ds_bpermute((lg * 4 + r) * 4, c.i);
      rv[r] = o.f;
    }

    int ktmax = (m0 + 15) >> 5;
    f32x4 yacc[4];
#pragma unroll
    for (int n2 = 0; n2 < 4; ++n2) yacc[n2] = zero4;
#pragma unroll
    for (int kt = 0; kt < 8; ++kt) {
      if (kt <= ktmax) {
        int n0 = 2 * kt, n1 = 2 * kt + 1;
        unsigned a01_0 = pk2(accs[n0][0], accs[n0][1]);
        unsigned a23_0 = pk2(accs[n0][2], accs[n0][3]);
        unsigned a01_1 = (n1 <= tile) ? pk2(accs[n1][0], accs[n1][1]) : 0u;
        unsigned a23_1 = (n1 <= tile) ? pk2(accs[n1][2], accs[n1][3]) : 0u;
        union { unsigned u[4]; bf16x8 v; } af;
        unsigned g0a = (unsigned)__builtin_amdgcn_ds_bpermute(addrA, (int)a01_0);
        unsigned g0b = (unsigned)__builtin_amdgcn_ds_bpermute(addrA, (int)a01_1);
        unsigned g1a = (unsigned)__builtin_amdgcn_ds_bpermute(addrA, (int)a23_0);
        unsigned g1b = (unsigned)__builtin_amdgcn_ds_bpermute(addrA, (int)a23_1);
        unsigned g2a = (unsigned)__builtin_amdgcn_ds_bpermute(addrB, (int)a01_0);
        unsigned g2b = (unsigned)__builtin_amdgcn_ds_bpermute(addrB, (int)a01_1);
        unsigned g3a = (unsigned)__builtin_amdgcn_ds_bpermute(addrB, (int)a23_0);
        unsigned g3b = (unsigned)__builtin_amdgcn_ds_bpermute(addrB, (int)a23_1);
        af.u[0] = selhi ? g0b : g0a;
        af.u[1] = selhi ? g1b : g1a;
        af.u[2] = selhi ? g2b : g2a;
        af.u[3] = selhi ? g3b : g3a;
        int ac = kt * 32 + lg * 8;
        __builtin_amdgcn_s_setprio(1);
#pragma unroll
        for (int n2 = 0; n2 < 4; ++n2) {
          int vn = n2 * 16 + lr;
          bf16x8 vb = *(bf16x8*)&Vt[vn * 256 + (((ac >> 3) ^ (vn & 7)) << 3)];
          yacc[n2] = __builtin_amdgcn_mfma_f32_16x16x32_bf16(af.v, vb, yacc[n2], 0, 0, 0);
        }
        __builtin_amdgcn_s_setprio(0);
      }
    }

#pragma unroll
    for (int n2 = 0; n2 < 4; ++n2) {
#pragma unroll
      for (int r = 0; r < 4; ++r) {
        int row = m0 + lg * 4 + r, d = n2 * 16 + lr;
        Y[((long)(bg * LS + row)) * C0 + h * HD + d] = f2bf(yacc[n2][r] * rv[r]);
      }
    }
  }
}

extern "C" void kernel_launch(void* const* d_in, const int* in_sizes, int n_in,
                              void* d_out, int out_size, void* d_ws, size_t ws_size,
                              hipStream_t stream) {
  (void)in_sizes; (void)n_in; (void)out_size; (void)ws_size;
  const float* x = (const float*)d_in[0];
  const float* w_qkv = (const float*)d_in[1];
  const float* w_ln = (const float*)d_in[2];
  const float* w_proj = (const float*)d_in[3];
  float* out = (float*)d_out;

  char* ws = (char*)d_ws;
  short* Xb      = (short*)(ws + 0);
  short* QKV     = (short*)(ws + 50331648);
  short* Yb      = (short*)(ws + 201326592);
  short* WqkvT   = (short*)(ws + 251658240);
  short* WprojT  = (short*)(ws + 255197184);
  float* cost    = (float*)(ws + 256376832);
  float* sint    = (float*)(ws + 256442368);

  cast_kernel<<<2048, 256, 0, stream>>>(x, Xb, (4 * 8192 * C0) / 4);
  cast_transpose_kernel<<<dim3(C3 / 32, C0 / 32), 256, 0, stream>>>(w_qkv, WqkvT, C0, C3);
  cast_transpose_kernel<<<dim3(C0 / 32, C0 / 32), 256, 0, stream>>>(w_proj, WprojT, C0, C0);
  rope_tab_kernel<<<256, 64, 0, stream>>>(cost, sint);

  // QKV = X @ Wqkv : M=32768, N=2304, K=768 ; grid 9*128=1152 (%8==0)
  gemm8p_kernel<0><<<(C3 / 256) * (32768 / 256), 512, 0, stream>>>(Xb, WqkvT, QKV,
                                                                   C3, C0, C3 / 256);
  norm_rope_kernel<<<32768, 384, 0, stream>>>(QKV, w_ln, cost, sint);
  attn_kernel<<<128 * NH, 512, 0, stream>>>(QKV, Yb);
  // out = Y @ Wproj : M=32768, N=768, K=768 ; grid 3*128=384 (%8==0)
  gemm8p_kernel<1><<<(C0 / 256) * (32768 / 256), 512, 0, stream>>>(Yb, WprojT, out,
                                                                   C0, C0, C0 / 256);
}